// Round 1
// baseline (50.177 us; speedup 1.0000x reference)
//
#include <hip/hip_runtime.h>
#include <math.h>

#define NB   4
#define NS   1024
#define DIN  256
#define DOUT 64
#define NQ   128
#define NK   6
#define NROW (NB*NS)        // 4096
#define NF   (NQ*NK*2)      // 1536 features per row

// ---------------------------------------------------------------------------
// K0: precompute W2 in interleaved layout W2p[(f>>2)*DOUT*4 + d*4 + (f&3)]
// feature ordering: f = (k*2 + c)*NQ + q ; c==0 pairs with sin((k+1)*a),
// c==1 pairs with cos((k+1)*a).
//   W2[f(c=0)][d] = A[d][q][k] * cos(Bp[d][q][k])
//   W2[f(c=1)][d] = A[d][q][k] * sin(Bp[d][q][k])
// ---------------------------------------------------------------------------
__global__ __launch_bounds__(256) void k0_weights(const float* __restrict__ A,
                                                  const float* __restrict__ Bp,
                                                  float* __restrict__ W2p) {
    int idx = blockIdx.x * 256 + threadIdx.x;     // [0, DOUT*NQ*NK)
    if (idx >= DOUT * NQ * NK) return;
    int d   = idx / (NQ * NK);
    int rem = idx - d * (NQ * NK);                // q*NK + k
    int q   = rem / NK;
    int k   = rem - q * NK;
    float a  = A[idx];
    float bp = Bp[idx];
    float sb = sinf(bp), cb = cosf(bp);
    int f0 = (k * 2 + 0) * NQ + q;
    int f1 = (k * 2 + 1) * NQ + q;
    W2p[((f0 >> 2) * DOUT + d) * 4 + (f0 & 3)] = a * cb;
    W2p[((f1 >> 2) * DOUT + d) * 4 + (f1 & 3)] = a * sb;
}

// ---------------------------------------------------------------------------
// K1: angle[row][q] = dot(X0[row], Wc_w[q]) + Wc_b[q] + w[q]*t[b]
// block = 256 threads, 16 rows per block; X0 tile staged in LDS (16 KiB).
// thread: q = tid&127, half h = tid>>7 handles 8 rows.
// ---------------------------------------------------------------------------
__global__ __launch_bounds__(256) void k1_angle(const float* __restrict__ X0,
                                                const float* __restrict__ tvec,
                                                const float* __restrict__ Wcw,
                                                const float* __restrict__ Wcb,
                                                const float* __restrict__ wq,
                                                float* __restrict__ angle) {
    __shared__ float Xs[16][DIN];                 // 16 KiB
    const int row0 = blockIdx.x * 16;
    const int tid  = threadIdx.x;

    // cooperative load: 16*256 floats = 1024 float4
    {
        const float4* src = (const float4*)(X0 + (size_t)row0 * DIN);
        float4* dst = (float4*)&Xs[0][0];
        #pragma unroll
        for (int j = 0; j < 4; ++j) dst[tid + j * 256] = src[tid + j * 256];
    }
    __syncthreads();

    const int q  = tid & 127;
    const int h  = tid >> 7;                      // 0..1
    const int r0 = h * 8;

    float4 acc[8];
    #pragma unroll
    for (int r = 0; r < 8; ++r) acc[r] = make_float4(0.f, 0.f, 0.f, 0.f);

    const float4* wrow = (const float4*)(Wcw + (size_t)q * DIN);
    #pragma unroll 4
    for (int i = 0; i < DIN / 4; ++i) {
        float4 wv = wrow[i];
        #pragma unroll
        for (int r = 0; r < 8; ++r) {
            float4 xv = *(const float4*)&Xs[r0 + r][i * 4];
            acc[r].x += wv.x * xv.x;
            acc[r].y += wv.y * xv.y;
            acc[r].z += wv.z * xv.z;
            acc[r].w += wv.w * xv.w;
        }
    }

    const int   b    = row0 >> 10;                // 1024 rows per batch
    const float bias = Wcb[q] + wq[q] * tvec[b];
    #pragma unroll
    for (int r = 0; r < 8; ++r) {
        float v = (acc[r].x + acc[r].y) + (acc[r].z + acc[r].w) + bias;
        angle[(size_t)(row0 + r0 + r) * NQ + q] = v;
    }
}

// ---------------------------------------------------------------------------
// K2: features (sincos + recurrence) -> LDS, then V = F * W2
// block = 256 threads, 8 rows per block; F tile in LDS = 8*1536*4 = 48 KiB.
// phase B: thread owns (d = tid&63, row-pair rg = tid>>6).
// ---------------------------------------------------------------------------
__global__ __launch_bounds__(256) void k2_fuse(const float* __restrict__ angle,
                                               const float* __restrict__ W2p,
                                               float* __restrict__ V) {
    __shared__ float F[8][NF];                    // 48 KiB
    const int row0 = blockIdx.x * 8;
    const int tid  = threadIdx.x;

    // ---- phase A: 1024 angles -> 12288 features -------------------------
    #pragma unroll
    for (int j = 0; j < 4; ++j) {
        int   li = tid + j * 256;                 // 0..1023
        int   r  = li >> 7;
        int   q  = li & 127;
        float a  = angle[(size_t)(row0 + r) * NQ + q];
        float s1, c1;
        __sincosf(a, &s1, &c1);
        float sk = s1, ck = c1;
        // f = (k*2+c)*NQ + q : lane-consecutive q -> conflict-free LDS writes
        F[r][0 * NQ + q] = sk;
        F[r][1 * NQ + q] = ck;
        #pragma unroll
        for (int k = 1; k < NK; ++k) {
            float sn = sk * c1 + ck * s1;         // sin((k+1)a)
            float cn = ck * c1 - sk * s1;         // cos((k+1)a)
            F[r][(k * 2 + 0) * NQ + q] = sn;
            F[r][(k * 2 + 1) * NQ + q] = cn;
            sk = sn; ck = cn;
        }
    }
    __syncthreads();

    // ---- phase B: V[r][d] = sum_f F[r][f] * W2[f][d] --------------------
    const int d  = tid & 63;
    const int rg = tid >> 6;                      // 0..3
    const int r0 = rg * 2;

    float4 a0 = make_float4(0.f, 0.f, 0.f, 0.f);
    float4 a1 = make_float4(0.f, 0.f, 0.f, 0.f);
    const float4* wp = (const float4*)W2p;        // [NF/4][DOUT] of float4
    #pragma unroll 4
    for (int f4 = 0; f4 < NF / 4; ++f4) {
        float4 wv = wp[(size_t)f4 * DOUT + d];    // coalesced 16B/lane
        float4 x0 = *(const float4*)&F[r0    ][f4 * 4];  // broadcast
        float4 x1 = *(const float4*)&F[r0 + 1][f4 * 4];  // broadcast
        a0.x += wv.x * x0.x; a0.y += wv.y * x0.y;
        a0.z += wv.z * x0.z; a0.w += wv.w * x0.w;
        a1.x += wv.x * x1.x; a1.y += wv.y * x1.y;
        a1.z += wv.z * x1.z; a1.w += wv.w * x1.w;
    }
    V[(size_t)(row0 + r0    ) * DOUT + d] = (a0.x + a0.y) + (a0.z + a0.w);
    V[(size_t)(row0 + r0 + 1) * DOUT + d] = (a1.x + a1.y) + (a1.z + a1.w);
}

// ---------------------------------------------------------------------------
extern "C" void kernel_launch(void* const* d_in, const int* in_sizes, int n_in,
                              void* d_out, int out_size, void* d_ws, size_t ws_size,
                              hipStream_t stream) {
    const float* X0   = (const float*)d_in[0];   // [4,1024,256]
    const float* tvec = (const float*)d_in[1];   // [4,1]
    const float* Wcw  = (const float*)d_in[2];   // [128,256]
    const float* Wcb  = (const float*)d_in[3];   // [128]
    const float* wq   = (const float*)d_in[4];   // [128]
    const float* A    = (const float*)d_in[5];   // [64,128,6]
    const float* Bp   = (const float*)d_in[6];   // [64,128,6]
    float*       V    = (float*)d_out;           // [4,1024,64]

    float* W2p   = (float*)d_ws;                            // 1536*64*4 = 393216 B
    float* angle = (float*)((char*)d_ws + (size_t)NF * DOUT * 4);  // 4096*128*4 = 2 MiB

    k0_weights<<<(DOUT * NQ * NK + 255) / 256, 256, 0, stream>>>(A, Bp, W2p);
    k1_angle  <<<NROW / 16, 256, 0, stream>>>(X0, tvec, Wcw, Wcb, wq, angle);
    k2_fuse   <<<NROW / 8,  256, 0, stream>>>(angle, W2p, V);
}

// Round 2
// 29.931 us; speedup vs baseline: 1.6764x; 1.6764x over previous
//
#include <hip/hip_runtime.h>
#include <math.h>

#define NB   4
#define NS   1024
#define DIN  256
#define DOUT 64
#define NQ   128
#define NK   6
#define NROW (NB*NS)        // 4096
#define NF   (NQ*NK*2)      // 1536 features per row
#define ROWS 16             // rows per block in fused kernel

typedef __attribute__((ext_vector_type(8))) short  short8;
typedef __attribute__((ext_vector_type(4))) float  f32x4;

__device__ __forceinline__ unsigned short f2bf(float x) {
    unsigned int u = __float_as_uint(x);
    u = (u + 0x7fffu + ((u >> 16) & 1u)) >> 16;   // RNE
    return (unsigned short)u;
}

// ---------------------------------------------------------------------------
// K0: W2T[d][f] bf16, f = (k*2+c)*NQ + q
//   c=0 (pairs sin((k+1)a)): A[d][q][k]*cos(Bp[d][q][k])
//   c=1 (pairs cos((k+1)a)): A[d][q][k]*sin(Bp[d][q][k])
// ---------------------------------------------------------------------------
__global__ __launch_bounds__(256) void k0_weights(const float* __restrict__ A,
                                                  const float* __restrict__ Bp,
                                                  unsigned short* __restrict__ W2T) {
    int idx = blockIdx.x * 256 + threadIdx.x;     // [0, DOUT*NQ*NK)
    if (idx >= DOUT * NQ * NK) return;
    int d   = idx / (NQ * NK);
    int rem = idx - d * (NQ * NK);                // q*NK + k
    int q   = rem / NK;
    int k   = rem - q * NK;
    float a  = A[idx];
    float bp = Bp[idx];
    float sb, cb;
    sincosf(bp, &sb, &cb);
    W2T[(size_t)d * NF + (k * 2 + 0) * NQ + q] = f2bf(a * cb);
    W2T[(size_t)d * NF + (k * 2 + 1) * NQ + q] = f2bf(a * sb);
}

// ---------------------------------------------------------------------------
// Fused kernel: 16 rows/block, 256 threads (4 waves).
//  1. stage X0[16][256] fp32 in LDS (first 16KB of the 48KB buffer)
//  2. angle: thread (q=tid&127, h=tid>>7) does rows h*8..h*8+7, fp32 dots
//  3. features -> bf16 into same LDS (48KB, XOR-swizzled rows)
//  4. MFMA: V[16][64] = F[16][1536] x W2T^T, wave w owns d-tile [16w,16w+16)
// ---------------------------------------------------------------------------
__global__ __launch_bounds__(256) void k_main(const float* __restrict__ X0,
                                              const float* __restrict__ tvec,
                                              const float* __restrict__ Wcw,
                                              const float* __restrict__ Wcb,
                                              const float* __restrict__ wq,
                                              const unsigned short* __restrict__ W2T,
                                              float* __restrict__ V) {
    __shared__ char smem[ROWS * NF * 2];          // 48 KiB
    const int row0 = blockIdx.x * ROWS;
    const int tid  = threadIdx.x;

    // ---- 1. stage X0 tile ------------------------------------------------
    {
        const float4* src = (const float4*)(X0 + (size_t)row0 * DIN);
        float4* dst = (float4*)smem;              // [16][256] fp32 = 16KB
        #pragma unroll
        for (int j = 0; j < 4; ++j) dst[tid + j * 256] = src[tid + j * 256];
    }
    __syncthreads();

    // ---- 2. angles (fp32, precision-critical) ----------------------------
    const int q = tid & 127;
    const int h = tid >> 7;                       // 0..1 -> rows h*8..h*8+7
    const float* Xs = (const float*)smem;

    float4 acc[8];
    #pragma unroll
    for (int r = 0; r < 8; ++r) acc[r] = make_float4(0.f, 0.f, 0.f, 0.f);

    const float4* wrow = (const float4*)(Wcw + (size_t)q * DIN);
    #pragma unroll 4
    for (int i = 0; i < DIN / 4; ++i) {
        float4 wv = wrow[i];
        #pragma unroll
        for (int r = 0; r < 8; ++r) {
            float4 xv = *(const float4*)&Xs[(h * 8 + r) * DIN + i * 4];
            acc[r].x += wv.x * xv.x;
            acc[r].y += wv.y * xv.y;
            acc[r].z += wv.z * xv.z;
            acc[r].w += wv.w * xv.w;
        }
    }
    const int   b    = row0 >> 10;                // 1024 rows per batch
    const float bias = Wcb[q] + wq[q] * tvec[b];
    float ang[8];
    #pragma unroll
    for (int r = 0; r < 8; ++r)
        ang[r] = (acc[r].x + acc[r].y) + (acc[r].z + acc[r].w) + bias;

    __syncthreads();                              // done reading Xs

    // ---- 3. features -> bf16 LDS, row-XOR swizzle ------------------------
    // F[r][f], f=(k*2+c)*NQ+q ; byte = r*3072 + f*2, ^((r&7)<<4)
    #pragma unroll
    for (int r = 0; r < 8; ++r) {
        const int row = h * 8 + r;
        const int sw  = (row & 7) << 4;
        char* base = smem + row * (NF * 2);
        float s1, c1;
        __sincosf(ang[r], &s1, &c1);
        float sk = s1, ck = c1;
        *(unsigned short*)(base + (((0 * NQ + q) * 2) ^ sw)) = f2bf(sk);
        *(unsigned short*)(base + (((1 * NQ + q) * 2) ^ sw)) = f2bf(ck);
        #pragma unroll
        for (int k = 1; k < NK; ++k) {
            float sn = sk * c1 + ck * s1;         // sin((k+1)a)
            float cn = ck * c1 - sk * s1;         // cos((k+1)a)
            *(unsigned short*)(base + ((((k * 2 + 0) * NQ + q) * 2) ^ sw)) = f2bf(sn);
            *(unsigned short*)(base + ((((k * 2 + 1) * NQ + q) * 2) ^ sw)) = f2bf(cn);
            sk = sn; ck = cn;
        }
    }
    __syncthreads();

    // ---- 4. MFMA: per wave, one 16x16 D-tile x 48 K-steps ----------------
    const int w    = tid >> 6;                    // wave id -> d-tile
    const int lane = tid & 63;
    const int arow = lane & 15;                   // A row (M)
    const int kgrp = lane >> 4;                   // 0..3
    const int asw  = (arow & 7) << 4;

    f32x4 cacc = {0.f, 0.f, 0.f, 0.f};
    const unsigned short* wbase = W2T + (size_t)(w * 16 + (lane & 15)) * NF + kgrp * 8;

    #pragma unroll 4
    for (int k0 = 0; k0 < NF; k0 += 32) {
        // A: lane holds F[arow][k0 + kgrp*8 + 0..7]
        int aoff = (arow * (NF * 2) + (k0 + kgrp * 8) * 2) ^ asw;
        short8 afrag = *(const short8*)(smem + aoff);
        // B: lane holds W2T[d = 16w+(lane&15)][k0 + kgrp*8 + 0..7]
        short8 bfrag = *(const short8*)(wbase + k0);
        cacc = __builtin_amdgcn_mfma_f32_16x16x32_bf16(afrag, bfrag, cacc, 0, 0, 0);
    }

    // D layout: col = lane&15 (-> d), row = kgrp*4 + j
    const int d = w * 16 + (lane & 15);
    #pragma unroll
    for (int j = 0; j < 4; ++j) {
        int rowo = kgrp * 4 + j;
        V[(size_t)(row0 + rowo) * DOUT + d] = cacc[j];
    }
}

// ---------------------------------------------------------------------------
extern "C" void kernel_launch(void* const* d_in, const int* in_sizes, int n_in,
                              void* d_out, int out_size, void* d_ws, size_t ws_size,
                              hipStream_t stream) {
    const float* X0   = (const float*)d_in[0];   // [4,1024,256]
    const float* tvec = (const float*)d_in[1];   // [4,1]
    const float* Wcw  = (const float*)d_in[2];   // [128,256]
    const float* Wcb  = (const float*)d_in[3];   // [128]
    const float* wq   = (const float*)d_in[4];   // [128]
    const float* A    = (const float*)d_in[5];   // [64,128,6]
    const float* Bp   = (const float*)d_in[6];   // [64,128,6]
    float*       V    = (float*)d_out;           // [4,1024,64]

    unsigned short* W2T = (unsigned short*)d_ws; // 64*1536*2 = 196608 B

    k0_weights<<<(DOUT * NQ * NK + 255) / 256, 256, 0, stream>>>(A, Bp, W2T);
    k_main    <<<NROW / ROWS, 256, 0, stream>>>(X0, tvec, Wcw, Wcb, wq, W2T, V);
}